// Round 12
// baseline (328.652 us; speedup 1.0000x reference)
//
#include <hip/hip_runtime.h>
#include <hip/hip_bf16.h>

typedef __hip_bfloat16 bf16;
typedef __attribute__((ext_vector_type(4))) float f32x4;
typedef __attribute__((ext_vector_type(16))) float f32x16;
typedef __attribute__((ext_vector_type(8))) short short8;
typedef __attribute__((ext_vector_type(4))) unsigned u32x4;

#define NHEAD 16
#define NKV 4
#define HD 128
#define BATCH 4
#define SEQ 2048
#define DIMM 2048
#define NROWS (BATCH*SEQ)        // 8192
#define QKVN (DIMM + 2*NKV*HD)   // 3072

__device__ inline void gload_lds16(const bf16* g, bf16* l) {
  __builtin_amdgcn_global_load_lds(
      (const __attribute__((address_space(1))) unsigned int*)g,
      (__attribute__((address_space(3))) unsigned int*)l, 16, 0, 0);
}

__device__ inline unsigned cvtpk(float a, float b) {
  unsigned r;
  asm("v_cvt_pk_bf16_f32 %0, %1, %2" : "=v"(r) : "v"(a), "v"(b));
  return r;
}
__device__ inline void pswap(unsigned& x, unsigned& y) {
  asm volatile("v_permlane32_swap_b32 %0, %1" : "+v"(x), "+v"(y));
}
__device__ inline float bf2f(short s) {
  return __uint_as_float(((unsigned)(unsigned short)s) << 16);
}
__device__ inline short f2bfbits(float f) {
  bf16 h = __float2bfloat16(f);
  return *reinterpret_cast<short*>(&h);
}

// ---------------- fused fp32 -> bf16 conversion (all 4 tensors) ----------------
#define CVTN0 ((size_t)NROWS * DIMM)
#define CVTN1 ((size_t)DIMM * DIMM)
#define CVTN2 ((size_t)2 * NKV * HD * DIMM)
#define CVTN3 ((size_t)DIMM * DIMM)
__global__ void cvt_all(const float* __restrict__ x, const float* __restrict__ wq,
                        const float* __restrict__ wkv, const float* __restrict__ wo,
                        bf16* __restrict__ xb, bf16* __restrict__ wqb,
                        bf16* __restrict__ wkvb, bf16* __restrict__ wob) {
  const size_t total = CVTN0 + CVTN1 + CVTN2 + CVTN3;
  for (size_t i = ((size_t)blockIdx.x * blockDim.x + threadIdx.x) * 4; i < total;
       i += (size_t)gridDim.x * blockDim.x * 4) {
    const float* s;
    bf16* d;
    size_t off;
    if (i < CVTN0) { s = x; d = xb; off = i; }
    else if (i < CVTN0 + CVTN1) { s = wq; d = wqb; off = i - CVTN0; }
    else if (i < CVTN0 + CVTN1 + CVTN2) { s = wkv; d = wkvb; off = i - CVTN0 - CVTN1; }
    else { s = wo; d = wob; off = i - CVTN0 - CVTN1 - CVTN2; }
    const float4 v = *reinterpret_cast<const float4*>(s + off);
    alignas(8) bf16 t[4] = {__float2bfloat16(v.x), __float2bfloat16(v.y),
                            __float2bfloat16(v.z), __float2bfloat16(v.w)};
    *reinterpret_cast<uint2*>(d + off) = *reinterpret_cast<const uint2*>(t);
  }
}

__device__ inline void store_c(float* p, float v) { *p = v; }
__device__ inline void store_c(bf16* p, float v) { *p = __float2bfloat16(v); }

// ---------------- GEMM 128x256 tile, BK=32, 8 waves, 3-plane pipeline ----------
// 3 LDS planes (72KB, 2 blocks/CU). stage(kt+2) targets plane (kt+2)%3 which was
// last read at phase kt-1 -> ONE barrier per phase, no mid-phase drain.
// Steady vmcnt(3) (2 planes x 3 loads in flight). lgkmcnt(0) folded before the
// barrier (free: reads already drained by MFMA deps; closes cross-wave
// read-vs-DMA window). STAGE issued before ds_reads (T3 recipe).
template <typename OutT>
__global__ __launch_bounds__(512, 4) void gemm128(
    const bf16* __restrict__ A, const bf16* __restrict__ B0,
    const bf16* __restrict__ B1, OutT* __restrict__ C,
    int N, int K, int Nsplit) {
  __shared__ __align__(16) short As[3][128 * 32];
  __shared__ __align__(16) short Bs[3][256 * 32];
  const int tid = threadIdx.x;
  const int w = tid >> 6, l = tid & 63;
  const int bid = blockIdx.x;
  const int xcd = bid & 7, q = bid >> 3;
  const int mi = q & 7, j = q >> 3;   // co-resident blocks (Δbid=256) share A-tile
  const int m0 = (xcd * 8 + mi) * 128, n0 = j * 256;
  const bf16* Ap = A + (size_t)m0 * K;
  const bf16* Bp = (n0 < Nsplit) ? (B0 + (size_t)n0 * K)
                                 : (B1 + (size_t)(n0 - Nsplit) * K);
  const int wr = w >> 2, wc = w & 3;  // wave grid 2(M) x 4(N), 64x64 each
  const int lr = l & 15, lc = l >> 4;
  const int swz = lc ^ (((lr >> 3) & 1) << 1);  // st_16x32 read swizzle

  f32x4 acc[4][4] = {};
  const int KT = K >> 5;  // BK=32

  auto stage = [&](int kt, int buf) {
    {  // A: 512 chunks of 8, 1 per thread
      const int cb = w * 64;
      const int ch = cb + l;
      const int row = ch >> 2, c = ch & 3;
      const int sc = c ^ (((row >> 3) & 1) << 1);
      gload_lds16(Ap + (size_t)row * K + kt * 32 + sc * 8, (bf16*)&As[buf][cb * 8]);
    }
#pragma unroll
    for (int jj = 0; jj < 2; ++jj) {  // B: 1024 chunks, 2 per thread
      const int cb = jj * 512 + w * 64;
      const int ch = cb + l;
      const int row = ch >> 2, c = ch & 3;
      const int sc = c ^ (((row >> 3) & 1) << 1);
      gload_lds16(Bp + (size_t)row * K + kt * 32 + sc * 8, (bf16*)&Bs[buf][cb * 8]);
    }
  };

  stage(0, 0);
  stage(1, 1);

  for (int kt = 0; kt < KT; ++kt) {
    const int cur = kt % 3;
    if (kt < KT - 1) {
      asm volatile("s_waitcnt vmcnt(3)" ::: "memory");
    } else {
      asm volatile("s_waitcnt vmcnt(0)" ::: "memory");
    }
    asm volatile("s_waitcnt lgkmcnt(0)" ::: "memory");  // ~free; safety vs DMA
    __builtin_amdgcn_s_barrier();
    __builtin_amdgcn_sched_barrier(0);

    if (kt + 2 < KT) stage(kt + 2, (kt + 2) % 3);

    short8 a[4], b[4];
#pragma unroll
    for (int mr = 0; mr < 4; ++mr)
      a[mr] = *(const short8*)&As[cur][(wr * 64 + mr * 16 + lr) * 32 + swz * 8];
#pragma unroll
    for (int nr = 0; nr < 4; ++nr)
      b[nr] = *(const short8*)&Bs[cur][(wc * 64 + nr * 16 + lr) * 32 + swz * 8];

    __builtin_amdgcn_s_setprio(1);
#pragma unroll
    for (int mr = 0; mr < 4; ++mr)
#pragma unroll
      for (int nr = 0; nr < 4; ++nr)
        acc[mr][nr] = __builtin_amdgcn_mfma_f32_16x16x32_bf16(
            a[mr], b[nr], acc[mr][nr], 0, 0, 0);
    __builtin_amdgcn_s_setprio(0);
  }

  const int cr4 = (l >> 4) * 4;
#pragma unroll
  for (int mr = 0; mr < 4; ++mr)
#pragma unroll
    for (int nr = 0; nr < 4; ++nr)
#pragma unroll
      for (int r = 0; r < 4; ++r) {
        const int row = m0 + wr * 64 + mr * 16 + cr4 + r;
        const int col = n0 + wc * 64 + nr * 16 + lr;
        store_c(&C[(size_t)row * N + col], acc[mr][nr][r]);
      }
}

// ---------------- fused RoPE (q,k) + V transpose ----------------
#define NVT ((SEQ / 64) * 2 * 16)            // 1024 vtrans blocks
#define NRP ((NROWS * 20 * 8) / 256)         // 5120 rope blocks
__global__ __launch_bounds__(256) void prep_kernel(bf16* __restrict__ qkv,
                                                   bf16* __restrict__ vtg) {
  if ((int)blockIdx.x < NVT) {
    __shared__ short T[64 * 72];
    const int bz = blockIdx.x >> 6;
    const int rem = blockIdx.x & 63;
    const int si = (rem >> 1) * 64;
    const int di = (rem & 1) * 64;
    const int b = bz >> 2, kvh = bz & 3;
    const int t = threadIdx.x;
    const int r = t >> 2, c2 = (t & 3) * 2;
    const bf16* src =
        qkv + (size_t)(b * SEQ + si + r) * QKVN + DIMM + NKV * HD + kvh * 128 + di;
#pragma unroll
    for (int i = 0; i < 2; ++i)
      *(short8*)&T[r * 72 + (c2 + i) * 8] = *(const short8*)(src + (c2 + i) * 8);
    __syncthreads();
#pragma unroll
    for (int i = 0; i < 2; ++i) {
      short8 v;
      const int s8 = (c2 + i) * 8;
#pragma unroll
      for (int j = 0; j < 8; ++j) v[j] = T[(s8 + j) * 72 + r];
      *(short8*)(vtg + (size_t)(kvh * 128 + di + r) * NROWS + b * SEQ + si + s8) = v;
    }
  } else {
    const int idx = ((int)blockIdx.x - NVT) * blockDim.x + threadIdx.x;
    const int dc = idx & 7;
    const int slot = (idx >> 3) % 20;
    const int row = idx / (8 * 20);
    const int col = (slot < 16) ? slot * 128 : DIMM + (slot - 16) * 128;
    const size_t base = (size_t)row * QKVN + col;
    const int pos = row & (SEQ - 1);
    const float psc = (slot < 16) ? 0.12751879895f : 1.0f;  // scale*log2e for Q
    short8 lo = *(const short8*)(qkv + base + dc * 8);
    short8 hi = *(const short8*)(qkv + base + 64 + dc * 8);
    short8 olo, ohi;
#pragma unroll
    for (int j = 0; j < 8; ++j) {
      const int d = dc * 8 + j;
      const float inv = exp2f((float)d * (-2.0f / 128.0f) * 13.287712379549449f);
      float sn, cs;
      __sincosf((float)pos * inv, &sn, &cs);
      const float flo = bf2f(lo[j]), fhi = bf2f(hi[j]);
      olo[j] = f2bfbits((flo * cs - fhi * sn) * psc);
      ohi[j] = f2bfbits((fhi * cs + flo * sn) * psc);
    }
    *(short8*)(qkv + base + dc * 8) = olo;
    *(short8*)(qkv + base + 64 + dc * 8) = ohi;
  }
}

// ---------------- Flash attention: 8 waves x 32 q-rows, KVBLK=64, swapped QK^T ----
__global__ __launch_bounds__(512, 2) void attn_kernel(
    const bf16* __restrict__ qkv, const bf16* __restrict__ vtg,
    bf16* __restrict__ aout) {
  __shared__ __align__(16) short KsL[2][64 * 128];
  __shared__ __align__(16) short VtL[2][128 * 64];
  const int tid = threadIdx.x, w = tid >> 6, l = tid & 63;
  const int lq = l & 31, hi = l >> 5;
  const int id = blockIdx.x;
  const int half = id >> 8, rr = id & 255;
  const int bh = (rr >> 3) + half * 32;
  const int j = rr & 7;
  const int qb = half ? j : 7 - j;
  const int b = bh >> 4, h = bh & 15, kvh = h >> 2;
  const int qw0 = qb * 256 + w * 32;
  const int qg = qw0 + lq;

  short8 qf[8];
  {
    const bf16* qptr = qkv + (size_t)(b * SEQ + qg) * QKVN + h * 128 + hi * 8;
#pragma unroll
    for (int s = 0; s < 8; ++s) qf[s] = *(const short8*)(qptr + s * 16);
  }

  f32x16 o[4] = {};
  float m = -1e30f, lsum = 0.f;
  const int ntiles = qb * 4 + 4;

  const bf16* Kgb = qkv + (size_t)(b * SEQ) * QKVN + DIMM + kvh * 128;
  const bf16* Vgb = vtg + (size_t)kvh * 128 * NROWS + b * SEQ;

  auto stage = [&](int kt, int buf) {
#pragma unroll
    for (int rd = 0; rd < 2; ++rd) {
      const int cb = (w * 2 + rd) * 64;
      {
        const int lc = cb + l, k = lc >> 4, c = lc & 15;
        gload_lds16(Kgb + (size_t)(kt * 64 + k) * QKVN + ((c ^ (k & 7)) * 8),
                    (bf16*)&KsL[buf][cb * 8]);
      }
      {
        const int lc = cb + l, d = lc >> 3, c = lc & 7;
        gload_lds16(Vgb + (size_t)d * NROWS + kt * 64 + ((c ^ (d & 7)) * 8),
                    (bf16*)&VtL[buf][cb * 8]);
      }
    }
  };

  stage(0, 0);
  asm volatile("s_waitcnt vmcnt(0)" ::: "memory");
  __builtin_amdgcn_s_barrier();
  __builtin_amdgcn_sched_barrier(0);

  for (int kt = 0; kt < ntiles; ++kt) {
    const int cur = kt & 1;
    if (kt + 1 < ntiles) stage(kt + 1, cur ^ 1);

    if (kt * 64 <= qw0 + 31) {
      f32x16 st[2];
#pragma unroll
      for (int ks = 0; ks < 2; ++ks) {
        const short* kb = &KsL[cur][(ks * 32 + lq) * 128];
        const int r7 = lq & 7;
        f32x16 acc = {};
        __builtin_amdgcn_s_setprio(1);
#pragma unroll
        for (int s = 0; s < 8; ++s) {
          const short8 kf = *(const short8*)&kb[((2 * s + hi) ^ r7) * 8];
          acc = __builtin_amdgcn_mfma_f32_32x32x16_bf16(kf, qf[s], acc, 0, 0, 0);
        }
        __builtin_amdgcn_s_setprio(0);
        st[ks] = acc;
      }
      if (kt * 64 + 63 > qw0) {
#pragma unroll
        for (int ks = 0; ks < 2; ++ks)
#pragma unroll
          for (int r = 0; r < 16; ++r) {
            const int kg = kt * 64 + ks * 32 + (r & 3) + 8 * (r >> 2) + 4 * hi;
            if (kg > qg) st[ks][r] = -1e30f;
          }
      }
      float t[16];
#pragma unroll
      for (int r = 0; r < 16; ++r) t[r] = fmaxf(st[0][r], st[1][r]);
#pragma unroll
      for (int d2 = 8; d2 > 0; d2 >>= 1)
#pragma unroll
        for (int r = 0; r < 8; ++r)
          if (r < d2) t[r] = fmaxf(t[r], t[r + d2]);
      float pm = fmaxf(t[0], __shfl_xor(t[0], 32));
      if (!__all(pm <= m + 11.0f)) {
        const float mnew = fmaxf(m, pm);
        const float fsc = __builtin_amdgcn_exp2f(m - mnew);
        m = mnew;
        lsum *= fsc;
#pragma unroll
        for (int r = 0; r < 16; ++r) {
          const float fq = __shfl(fsc, (r & 3) + 8 * (r >> 2) + 4 * hi);
#pragma unroll
          for (int db = 0; db < 4; ++db) o[db][r] *= fq;
        }
      }
      short8 pa[4];
#pragma unroll
      for (int ks = 0; ks < 2; ++ks) {
        float p[16];
        float s0 = 0.f, s1 = 0.f, s2 = 0.f, s3 = 0.f;
#pragma unroll
        for (int r = 0; r < 16; r += 4) {
          p[r] = __builtin_amdgcn_exp2f(st[ks][r] - m);         s0 += p[r];
          p[r + 1] = __builtin_amdgcn_exp2f(st[ks][r + 1] - m); s1 += p[r + 1];
          p[r + 2] = __builtin_amdgcn_exp2f(st[ks][r + 2] - m); s2 += p[r + 2];
          p[r + 3] = __builtin_amdgcn_exp2f(st[ks][r + 3] - m); s3 += p[r + 3];
        }
        lsum += (s0 + s1) + (s2 + s3);
#pragma unroll
        for (int hf = 0; hf < 2; ++hf) {
          unsigned x0 = cvtpk(p[hf * 8 + 0], p[hf * 8 + 1]);
          unsigned y0 = cvtpk(p[hf * 8 + 4], p[hf * 8 + 5]);
          unsigned x1 = cvtpk(p[hf * 8 + 2], p[hf * 8 + 3]);
          unsigned y1 = cvtpk(p[hf * 8 + 6], p[hf * 8 + 7]);
          pswap(x0, y0);
          pswap(x1, y1);
          union { u32x4 u; short8 s; } pk;
          pk.u = u32x4{x0, x1, y0, y1};
          pa[ks * 2 + hf] = pk.s;
        }
      }
      __builtin_amdgcn_s_setprio(1);
#pragma unroll
      for (int s = 0; s < 4; ++s) {
        const int cc = ((2 * s + hi) ^ (lq & 7)) * 8;
#pragma unroll
        for (int db = 0; db < 4; ++db) {
          const short8 vb = *(const short8*)&VtL[cur][(db * 32 + lq) * 64 + cc];
          o[db] = __builtin_amdgcn_mfma_f32_32x32x16_bf16(pa[s], vb, o[db], 0, 0, 0);
        }
      }
      __builtin_amdgcn_s_setprio(0);
    }

    asm volatile("s_waitcnt vmcnt(0)" ::: "memory");
    __builtin_amdgcn_s_barrier();
    __builtin_amdgcn_sched_barrier(0);
  }

  const float lf = lsum + __shfl_xor(lsum, 32);
#pragma unroll
  for (int r = 0; r < 16; ++r) {
    const int qr = (r & 3) + 8 * (r >> 2) + 4 * hi;
    const float linv = 1.0f / __shfl(lf, qr);
    bf16* op = aout + (size_t)(b * SEQ + qw0 + qr) * DIMM + h * 128 + lq;
#pragma unroll
    for (int db = 0; db < 4; ++db)
      op[db * 32] = __float2bfloat16(o[db][r] * linv);
  }
}

// ---------------- launcher ----------------
extern "C" void kernel_launch(void* const* d_in, const int* in_sizes, int n_in,
                              void* d_out, int out_size, void* d_ws, size_t ws_size,
                              hipStream_t stream) {
  const float* x = (const float*)d_in[0];
  const float* Wq = (const float*)d_in[1];
  const float* Wkv = (const float*)d_in[2];
  const float* Wo = (const float*)d_in[3];
  float* out = (float*)d_out;

  bf16* xb = (bf16*)d_ws;                          // 8192*2048
  bf16* Wqb = xb + (size_t)NROWS * DIMM;           // 2048*2048
  bf16* Wkvb = Wqb + (size_t)DIMM * DIMM;          // 1024*2048
  bf16* Wob = Wkvb + (size_t)2 * NKV * HD * DIMM;  // 2048*2048
  bf16* attn = Wob + (size_t)DIMM * DIMM;          // 8192*2048
  bf16* qkv = (bf16*)d_out;                        // 50.3MB scratch in d_out
  bf16* vtg = (bf16*)d_out + (size_t)NROWS * QKVN; // 8MB more, still in d_out

  cvt_all<<<2048, 256, 0, stream>>>(x, Wq, Wkv, Wo, xb, Wqb, Wkvb, Wob);

  gemm128<bf16><<<dim3((NROWS / 128) * (QKVN / 256)), 512, 0, stream>>>(
      xb, Wqb, Wkvb, qkv, QKVN, DIMM, DIMM);

  prep_kernel<<<NVT + NRP, 256, 0, stream>>>(qkv, vtg);

  attn_kernel<<<dim3(512), 512, 0, stream>>>(qkv, vtg, attn);

  gemm128<float><<<dim3((NROWS / 128) * (DIMM / 256)), 512, 0, stream>>>(
      attn, Wob, Wob, out, DIMM, DIMM, DIMM);
}

// Round 13
// 325.487 us; speedup vs baseline: 1.0097x; 1.0097x over previous
//
#include <hip/hip_runtime.h>
#include <hip/hip_bf16.h>

typedef __hip_bfloat16 bf16;
typedef __attribute__((ext_vector_type(4))) float f32x4;
typedef __attribute__((ext_vector_type(16))) float f32x16;
typedef __attribute__((ext_vector_type(8))) short short8;
typedef __attribute__((ext_vector_type(4))) unsigned u32x4;

#define NHEAD 16
#define NKV 4
#define HD 128
#define BATCH 4
#define SEQ 2048
#define DIMM 2048
#define NROWS (BATCH*SEQ)        // 8192
#define QKVN (DIMM + 2*NKV*HD)   // 3072

#define SBAR0 __builtin_amdgcn_sched_barrier(0)
#define BAR   __builtin_amdgcn_s_barrier()
#define LGKM0 asm volatile("s_waitcnt lgkmcnt(0)" ::: "memory")

__device__ inline void gload_lds16(const bf16* g, bf16* l) {
  __builtin_amdgcn_global_load_lds(
      (const __attribute__((address_space(1))) unsigned int*)g,
      (__attribute__((address_space(3))) unsigned int*)l, 16, 0, 0);
}

__device__ inline unsigned cvtpk(float a, float b) {
  unsigned r;
  asm("v_cvt_pk_bf16_f32 %0, %1, %2" : "=v"(r) : "v"(a), "v"(b));
  return r;
}
__device__ inline void pswap(unsigned& x, unsigned& y) {
  asm volatile("v_permlane32_swap_b32 %0, %1" : "+v"(x), "+v"(y));
}
__device__ inline float bf2f(short s) {
  return __uint_as_float(((unsigned)(unsigned short)s) << 16);
}
__device__ inline short f2bfbits(float f) {
  bf16 h = __float2bfloat16(f);
  return *reinterpret_cast<short*>(&h);
}

// ---------------- fused fp32 -> bf16 conversion (all 4 tensors) ----------------
#define CVTN0 ((size_t)NROWS * DIMM)
#define CVTN1 ((size_t)DIMM * DIMM)
#define CVTN2 ((size_t)2 * NKV * HD * DIMM)
#define CVTN3 ((size_t)DIMM * DIMM)
__global__ void cvt_all(const float* __restrict__ x, const float* __restrict__ wq,
                        const float* __restrict__ wkv, const float* __restrict__ wo,
                        bf16* __restrict__ xb, bf16* __restrict__ wqb,
                        bf16* __restrict__ wkvb, bf16* __restrict__ wob) {
  const size_t total = CVTN0 + CVTN1 + CVTN2 + CVTN3;
  for (size_t i = ((size_t)blockIdx.x * blockDim.x + threadIdx.x) * 4; i < total;
       i += (size_t)gridDim.x * blockDim.x * 4) {
    const float* s;
    bf16* d;
    size_t off;
    if (i < CVTN0) { s = x; d = xb; off = i; }
    else if (i < CVTN0 + CVTN1) { s = wq; d = wqb; off = i - CVTN0; }
    else if (i < CVTN0 + CVTN1 + CVTN2) { s = wkv; d = wkvb; off = i - CVTN0 - CVTN1; }
    else { s = wo; d = wob; off = i - CVTN0 - CVTN1 - CVTN2; }
    const float4 v = *reinterpret_cast<const float4*>(s + off);
    alignas(8) bf16 t[4] = {__float2bfloat16(v.x), __float2bfloat16(v.y),
                            __float2bfloat16(v.z), __float2bfloat16(v.w)};
    *reinterpret_cast<uint2*>(d + off) = *reinterpret_cast<const uint2*>(t);
  }
}

__device__ inline void store_c(float* p, float v) { *p = v; }
__device__ inline void store_c(bf16* p, float v) { *p = __float2bfloat16(v); }

// ---------------- GEMM 256x256, BK=64, 8 waves, m201 8-phase schedule ----------
// LDS: As/Bs[2 dbuf][2 kk][256 rows][32 shorts] = 128KB, 1 block/CU.
// Even tiles -> dbuf0, odd -> dbuf1. 8 phases per 2 K-tiles; per phase:
// {ds_reads (12/4/8/0, frags reused) ; stage 1 plane (2 gload_lds) ;
//  [vmcnt(4) at p3,p7] ; barrier ; lgkmcnt(0) ; 16 MFMA setprio ; barrier}.
// Stage order p0..p7: Ak0(t+1),Ak1(t+1),Bk0(t+2),Bk1(t+2),Ak0(t+2),Ak1(t+2),
// Bk0(t+3),Bk1(t+3) — race-checked safe under vmcnt(4); last iter vmcnt(0).
template <typename OutT>
__global__ __launch_bounds__(512, 2) void gemm256(
    const bf16* __restrict__ A, const bf16* __restrict__ B0,
    const bf16* __restrict__ B1, OutT* __restrict__ C,
    int N, int K, int Nsplit, int MI8) {
  __shared__ __align__(16) short As[2][2][256 * 32];
  __shared__ __align__(16) short Bs[2][2][256 * 32];
  const int tid = threadIdx.x;
  const int w = tid >> 6, l = tid & 63;
  const int bid = blockIdx.x;
  const int xcd = bid & 7, q = bid >> 3;
  const int mi = q % MI8, j = q / MI8;
  const int m0 = (xcd * MI8 + mi) * 256, n0 = j * 256;
  const bf16* Ap = A + (size_t)m0 * K;
  const bf16* Bp = (n0 < Nsplit) ? (B0 + (size_t)n0 * K)
                                 : (B1 + (size_t)(n0 - Nsplit) * K);
  const int wr = w >> 2, wc = w & 3;  // wave grid 2(M) x 4(N): per-wave 128x64
  const int lr = l & 15, lc = l >> 4;
  const int swz = lc ^ (((lr >> 3) & 1) << 1);  // st_16x32 read swizzle (0-conflict, R7+)

  f32x4 acc[8][4] = {};
  const int KT = K >> 6;    // 64-wide K-tiles
  const int NT2 = KT >> 1;  // iterations (2 tiles each)

  auto stageA = [&](int t, int kk) {
    if (t >= KT) return;
#pragma unroll
    for (int jj = 0; jj < 2; ++jj) {
      const int cb = jj * 512 + w * 64;         // wave-uniform granule base
      const int G = cb + l;
      const int row = G >> 2, c = G & 3;
      const int sc = c ^ (((row >> 3) & 1) << 1);
      gload_lds16(Ap + (size_t)row * K + t * 64 + kk * 32 + sc * 8,
                  (bf16*)&As[t & 1][kk][cb * 8]);
    }
  };
  auto stageB = [&](int t, int kk) {
    if (t >= KT) return;
#pragma unroll
    for (int jj = 0; jj < 2; ++jj) {
      const int cb = jj * 512 + w * 64;
      const int G = cb + l;
      const int row = G >> 2, c = G & 3;
      const int sc = c ^ (((row >> 3) & 1) << 1);
      gload_lds16(Bp + (size_t)row * K + t * 64 + kk * 32 + sc * 8,
                  (bf16*)&Bs[t & 1][kk][cb * 8]);
    }
  };

  short8 afr[8];   // [mr*2+kk], current m-subtile
  short8 bfr[8];   // [nsub*4 + nr*2 + kk], both n-subtiles live
  auto readA = [&](int buf, int msub) {
#pragma unroll
    for (int z = 0; z < 8; ++z) {
      const int mr = z >> 1, kk = z & 1;
      afr[z] = *(const short8*)&As[buf][kk]
          [(wr * 128 + msub * 64 + mr * 16 + lr) * 32 + swz * 8];
    }
  };
  auto readB = [&](int buf, int nsub) {
#pragma unroll
    for (int z = 0; z < 4; ++z) {
      const int nr = z >> 1, kk = z & 1;
      bfr[nsub * 4 + z] = *(const short8*)&Bs[buf][kk]
          [(wc * 64 + nsub * 32 + nr * 16 + lr) * 32 + swz * 8];
    }
  };
  auto mmac = [&](int msub, int nsub) {
    __builtin_amdgcn_s_setprio(1);
#pragma unroll
    for (int kk = 0; kk < 2; ++kk)
#pragma unroll
      for (int mr = 0; mr < 4; ++mr)
#pragma unroll
        for (int nr = 0; nr < 2; ++nr)
          acc[msub * 4 + mr][nsub * 2 + nr] =
              __builtin_amdgcn_mfma_f32_16x16x32_bf16(
                  afr[mr * 2 + kk], bfr[nsub * 4 + nr * 2 + kk],
                  acc[msub * 4 + mr][nsub * 2 + nr], 0, 0, 0);
    __builtin_amdgcn_s_setprio(0);
  };

  // prologue: tile0 (A,B all planes) + tile1 B planes; drain tile0, keep 2 in flight
  stageA(0, 0); stageA(0, 1); stageB(0, 0); stageB(0, 1);
  stageB(1, 0); stageB(1, 1);
  asm volatile("s_waitcnt vmcnt(4)" ::: "memory");
  BAR; SBAR0;

  for (int T = 0; T < NT2; ++T) {
    const int t0 = 2 * T, t1 = 2 * T + 1;
    const bool last = (T == NT2 - 1);
    // ---- phase 0: tile t0, Q(m0,n0) ----
    readA(0, 0); readB(0, 0); stageA(t1, 0);
    SBAR0; BAR; LGKM0; SBAR0; mmac(0, 0); BAR;
    // ---- phase 1: Q(m0,n1) ----
    readB(0, 1); stageA(t1, 1);
    SBAR0; BAR; LGKM0; SBAR0; mmac(0, 1); BAR;
    // ---- phase 2: Q(m1,n0) ----
    readA(0, 1); stageB(t0 + 2, 0);
    SBAR0; BAR; LGKM0; SBAR0; mmac(1, 0); BAR;
    // ---- phase 3: Q(m1,n1) + counted vmcnt ----
    stageB(t0 + 2, 1);
    if (last) { asm volatile("s_waitcnt vmcnt(0)" ::: "memory"); }
    else      { asm volatile("s_waitcnt vmcnt(4)" ::: "memory"); }
    SBAR0; BAR; LGKM0; SBAR0; mmac(1, 1); BAR;
    // ---- phase 4: tile t1, Q(m0,n0) ----
    readA(1, 0); readB(1, 0); stageA(t0 + 2, 0);
    SBAR0; BAR; LGKM0; SBAR0; mmac(0, 0); BAR;
    // ---- phase 5: Q(m0,n1) ----
    readB(1, 1); stageA(t0 + 2, 1);
    SBAR0; BAR; LGKM0; SBAR0; mmac(0, 1); BAR;
    // ---- phase 6: Q(m1,n0) ----
    readA(1, 1); stageB(t1 + 2, 0);
    SBAR0; BAR; LGKM0; SBAR0; mmac(1, 0); BAR;
    // ---- phase 7: Q(m1,n1) + counted vmcnt ----
    stageB(t1 + 2, 1);
    if (last) { asm volatile("s_waitcnt vmcnt(0)" ::: "memory"); }
    else      { asm volatile("s_waitcnt vmcnt(4)" ::: "memory"); }
    SBAR0; BAR; LGKM0; SBAR0; mmac(1, 1); BAR;
  }

  const int cr4 = (l >> 4) * 4;
#pragma unroll
  for (int mr = 0; mr < 8; ++mr)
#pragma unroll
    for (int nr = 0; nr < 4; ++nr)
#pragma unroll
      for (int r = 0; r < 4; ++r) {
        const int row = m0 + wr * 128 + mr * 16 + cr4 + r;
        const int col = n0 + wc * 64 + nr * 16 + lr;
        store_c(&C[(size_t)row * N + col], acc[mr][nr][r]);
      }
}

// ---------------- fused RoPE (q,k) + V transpose ----------------
#define NVT ((SEQ / 64) * 2 * 16)            // 1024 vtrans blocks
#define NRP ((NROWS * 20 * 8) / 256)         // 5120 rope blocks
__global__ __launch_bounds__(256) void prep_kernel(bf16* __restrict__ qkv,
                                                   bf16* __restrict__ vtg) {
  if ((int)blockIdx.x < NVT) {
    __shared__ short T[64 * 72];
    const int bz = blockIdx.x >> 6;
    const int rem = blockIdx.x & 63;
    const int si = (rem >> 1) * 64;
    const int di = (rem & 1) * 64;
    const int b = bz >> 2, kvh = bz & 3;
    const int t = threadIdx.x;
    const int r = t >> 2, c2 = (t & 3) * 2;
    const bf16* src =
        qkv + (size_t)(b * SEQ + si + r) * QKVN + DIMM + NKV * HD + kvh * 128 + di;
#pragma unroll
    for (int i = 0; i < 2; ++i)
      *(short8*)&T[r * 72 + (c2 + i) * 8] = *(const short8*)(src + (c2 + i) * 8);
    __syncthreads();
#pragma unroll
    for (int i = 0; i < 2; ++i) {
      short8 v;
      const int s8 = (c2 + i) * 8;
#pragma unroll
      for (int j = 0; j < 8; ++j) v[j] = T[(s8 + j) * 72 + r];
      *(short8*)(vtg + (size_t)(kvh * 128 + di + r) * NROWS + b * SEQ + si + s8) = v;
    }
  } else {
    const int idx = ((int)blockIdx.x - NVT) * blockDim.x + threadIdx.x;
    const int dc = idx & 7;
    const int slot = (idx >> 3) % 20;
    const int row = idx / (8 * 20);
    const int col = (slot < 16) ? slot * 128 : DIMM + (slot - 16) * 128;
    const size_t base = (size_t)row * QKVN + col;
    const int pos = row & (SEQ - 1);
    const float psc = (slot < 16) ? 0.12751879895f : 1.0f;  // scale*log2e for Q
    short8 lo = *(const short8*)(qkv + base + dc * 8);
    short8 hi = *(const short8*)(qkv + base + 64 + dc * 8);
    short8 olo, ohi;
#pragma unroll
    for (int j = 0; j < 8; ++j) {
      const int d = dc * 8 + j;
      const float inv = exp2f((float)d * (-2.0f / 128.0f) * 13.287712379549449f);
      float sn, cs;
      __sincosf((float)pos * inv, &sn, &cs);
      const float flo = bf2f(lo[j]), fhi = bf2f(hi[j]);
      olo[j] = f2bfbits((flo * cs - fhi * sn) * psc);
      ohi[j] = f2bfbits((fhi * cs + flo * sn) * psc);
    }
    *(short8*)(qkv + base + dc * 8) = olo;
    *(short8*)(qkv + base + 64 + dc * 8) = ohi;
  }
}

// ---------------- Flash attention: 8 waves x 32 q-rows, KVBLK=64, swapped QK^T ----
__global__ __launch_bounds__(512, 2) void attn_kernel(
    const bf16* __restrict__ qkv, const bf16* __restrict__ vtg,
    bf16* __restrict__ aout) {
  __shared__ __align__(16) short KsL[2][64 * 128];
  __shared__ __align__(16) short VtL[2][128 * 64];
  const int tid = threadIdx.x, w = tid >> 6, l = tid & 63;
  const int lq = l & 31, hi = l >> 5;
  const int id = blockIdx.x;
  const int half = id >> 8, rr = id & 255;
  const int bh = (rr >> 3) + half * 32;
  const int j = rr & 7;
  const int qb = half ? j : 7 - j;
  const int b = bh >> 4, h = bh & 15, kvh = h >> 2;
  const int qw0 = qb * 256 + w * 32;
  const int qg = qw0 + lq;

  short8 qf[8];
  {
    const bf16* qptr = qkv + (size_t)(b * SEQ + qg) * QKVN + h * 128 + hi * 8;
#pragma unroll
    for (int s = 0; s < 8; ++s) qf[s] = *(const short8*)(qptr + s * 16);
  }

  f32x16 o[4] = {};
  float m = -1e30f, lsum = 0.f;
  const int ntiles = qb * 4 + 4;

  const bf16* Kgb = qkv + (size_t)(b * SEQ) * QKVN + DIMM + kvh * 128;
  const bf16* Vgb = vtg + (size_t)kvh * 128 * NROWS + b * SEQ;

  auto stage = [&](int kt, int buf) {
#pragma unroll
    for (int rd = 0; rd < 2; ++rd) {
      const int cb = (w * 2 + rd) * 64;
      {
        const int lc = cb + l, k = lc >> 4, c = lc & 15;
        gload_lds16(Kgb + (size_t)(kt * 64 + k) * QKVN + ((c ^ (k & 7)) * 8),
                    (bf16*)&KsL[buf][cb * 8]);
      }
      {
        const int lc = cb + l, d = lc >> 3, c = lc & 7;
        gload_lds16(Vgb + (size_t)d * NROWS + kt * 64 + ((c ^ (d & 7)) * 8),
                    (bf16*)&VtL[buf][cb * 8]);
      }
    }
  };

  stage(0, 0);
  asm volatile("s_waitcnt vmcnt(0)" ::: "memory");
  __builtin_amdgcn_s_barrier();
  __builtin_amdgcn_sched_barrier(0);

  for (int kt = 0; kt < ntiles; ++kt) {
    const int cur = kt & 1;
    if (kt + 1 < ntiles) stage(kt + 1, cur ^ 1);

    if (kt * 64 <= qw0 + 31) {
      f32x16 st[2];
#pragma unroll
      for (int ks = 0; ks < 2; ++ks) {
        const short* kb = &KsL[cur][(ks * 32 + lq) * 128];
        const int r7 = lq & 7;
        f32x16 acc = {};
        __builtin_amdgcn_s_setprio(1);
#pragma unroll
        for (int s = 0; s < 8; ++s) {
          const short8 kf = *(const short8*)&kb[((2 * s + hi) ^ r7) * 8];
          acc = __builtin_amdgcn_mfma_f32_32x32x16_bf16(kf, qf[s], acc, 0, 0, 0);
        }
        __builtin_amdgcn_s_setprio(0);
        st[ks] = acc;
      }
      if (kt * 64 + 63 > qw0) {
#pragma unroll
        for (int ks = 0; ks < 2; ++ks)
#pragma unroll
          for (int r = 0; r < 16; ++r) {
            const int kg = kt * 64 + ks * 32 + (r & 3) + 8 * (r >> 2) + 4 * hi;
            if (kg > qg) st[ks][r] = -1e30f;
          }
      }
      float t[16];
#pragma unroll
      for (int r = 0; r < 16; ++r) t[r] = fmaxf(st[0][r], st[1][r]);
#pragma unroll
      for (int d2 = 8; d2 > 0; d2 >>= 1)
#pragma unroll
        for (int r = 0; r < 8; ++r)
          if (r < d2) t[r] = fmaxf(t[r], t[r + d2]);
      float pm = fmaxf(t[0], __shfl_xor(t[0], 32));
      if (!__all(pm <= m + 11.0f)) {
        const float mnew = fmaxf(m, pm);
        const float fsc = __builtin_amdgcn_exp2f(m - mnew);
        m = mnew;
        lsum *= fsc;
#pragma unroll
        for (int r = 0; r < 16; ++r) {
          const float fq = __shfl(fsc, (r & 3) + 8 * (r >> 2) + 4 * hi);
#pragma unroll
          for (int db = 0; db < 4; ++db) o[db][r] *= fq;
        }
      }
      short8 pa[4];
#pragma unroll
      for (int ks = 0; ks < 2; ++ks) {
        float p[16];
        float s0 = 0.f, s1 = 0.f, s2 = 0.f, s3 = 0.f;
#pragma unroll
        for (int r = 0; r < 16; r += 4) {
          p[r] = __builtin_amdgcn_exp2f(st[ks][r] - m);         s0 += p[r];
          p[r + 1] = __builtin_amdgcn_exp2f(st[ks][r + 1] - m); s1 += p[r + 1];
          p[r + 2] = __builtin_amdgcn_exp2f(st[ks][r + 2] - m); s2 += p[r + 2];
          p[r + 3] = __builtin_amdgcn_exp2f(st[ks][r + 3] - m); s3 += p[r + 3];
        }
        lsum += (s0 + s1) + (s2 + s3);
#pragma unroll
        for (int hf = 0; hf < 2; ++hf) {
          unsigned x0 = cvtpk(p[hf * 8 + 0], p[hf * 8 + 1]);
          unsigned y0 = cvtpk(p[hf * 8 + 4], p[hf * 8 + 5]);
          unsigned x1 = cvtpk(p[hf * 8 + 2], p[hf * 8 + 3]);
          unsigned y1 = cvtpk(p[hf * 8 + 6], p[hf * 8 + 7]);
          pswap(x0, y0);
          pswap(x1, y1);
          union { u32x4 u; short8 s; } pk;
          pk.u = u32x4{x0, x1, y0, y1};
          pa[ks * 2 + hf] = pk.s;
        }
      }
      __builtin_amdgcn_s_setprio(1);
#pragma unroll
      for (int s = 0; s < 4; ++s) {
        const int cc = ((2 * s + hi) ^ (lq & 7)) * 8;
#pragma unroll
        for (int db = 0; db < 4; ++db) {
          const short8 vb = *(const short8*)&VtL[cur][(db * 32 + lq) * 64 + cc];
          o[db] = __builtin_amdgcn_mfma_f32_32x32x16_bf16(pa[s], vb, o[db], 0, 0, 0);
        }
      }
      __builtin_amdgcn_s_setprio(0);
    }

    asm volatile("s_waitcnt vmcnt(0)" ::: "memory");
    __builtin_amdgcn_s_barrier();
    __builtin_amdgcn_sched_barrier(0);
  }

  const float lf = lsum + __shfl_xor(lsum, 32);
#pragma unroll
  for (int r = 0; r < 16; ++r) {
    const int qr = (r & 3) + 8 * (r >> 2) + 4 * hi;
    const float linv = 1.0f / __shfl(lf, qr);
    bf16* op = aout + (size_t)(b * SEQ + qw0 + qr) * DIMM + h * 128 + lq;
#pragma unroll
    for (int db = 0; db < 4; ++db)
      op[db * 32] = __float2bfloat16(o[db][r] * linv);
  }
}

// ---------------- launcher ----------------
extern "C" void kernel_launch(void* const* d_in, const int* in_sizes, int n_in,
                              void* d_out, int out_size, void* d_ws, size_t ws_size,
                              hipStream_t stream) {
  const float* x = (const float*)d_in[0];
  const float* Wq = (const float*)d_in[1];
  const float* Wkv = (const float*)d_in[2];
  const float* Wo = (const float*)d_in[3];
  float* out = (float*)d_out;

  bf16* xb = (bf16*)d_ws;                          // 8192*2048
  bf16* Wqb = xb + (size_t)NROWS * DIMM;           // 2048*2048
  bf16* Wkvb = Wqb + (size_t)DIMM * DIMM;          // 1024*2048
  bf16* Wob = Wkvb + (size_t)2 * NKV * HD * DIMM;  // 2048*2048
  bf16* attn = Wob + (size_t)DIMM * DIMM;          // 8192*2048
  bf16* qkv = (bf16*)d_out;                        // 50.3MB scratch in d_out
  bf16* vtg = (bf16*)d_out + (size_t)NROWS * QKVN; // 8MB more, still in d_out

  cvt_all<<<2048, 256, 0, stream>>>(x, Wq, Wkv, Wo, xb, Wqb, Wkvb, Wob);

  gemm256<bf16><<<dim3((NROWS / 256) * (QKVN / 256)), 512, 0, stream>>>(
      xb, Wqb, Wkvb, qkv, QKVN, DIMM, DIMM, (NROWS / 256) / 8);

  prep_kernel<<<NVT + NRP, 256, 0, stream>>>(qkv, vtg);

  attn_kernel<<<dim3(512), 512, 0, stream>>>(qkv, vtg, attn);

  gemm256<float><<<dim3((NROWS / 256) * (DIMM / 256)), 512, 0, stream>>>(
      attn, Wob, Wob, out, DIMM, DIMM, DIMM, (NROWS / 256) / 8);
}

// Round 14
// 297.680 us; speedup vs baseline: 1.1040x; 1.0934x over previous
//
#include <hip/hip_runtime.h>
#include <hip/hip_bf16.h>

typedef __hip_bfloat16 bf16;
typedef __attribute__((ext_vector_type(4))) float f32x4;
typedef __attribute__((ext_vector_type(16))) float f32x16;
typedef __attribute__((ext_vector_type(8))) short short8;
typedef __attribute__((ext_vector_type(4))) unsigned u32x4;

#define NHEAD 16
#define NKV 4
#define HD 128
#define BATCH 4
#define SEQ 2048
#define DIMM 2048
#define NROWS (BATCH*SEQ)        // 8192
#define QKVN (DIMM + 2*NKV*HD)   // 3072

__device__ inline void gload_lds16(const bf16* g, bf16* l) {
  __builtin_amdgcn_global_load_lds(
      (const __attribute__((address_space(1))) unsigned int*)g,
      (__attribute__((address_space(3))) unsigned int*)l, 16, 0, 0);
}

__device__ inline unsigned cvtpk(float a, float b) {
  unsigned r;
  asm("v_cvt_pk_bf16_f32 %0, %1, %2" : "=v"(r) : "v"(a), "v"(b));
  return r;
}
__device__ inline void pswap(unsigned& x, unsigned& y) {
  asm volatile("v_permlane32_swap_b32 %0, %1" : "+v"(x), "+v"(y));
}
__device__ inline float bf2f(short s) {
  return __uint_as_float(((unsigned)(unsigned short)s) << 16);
}
__device__ inline short f2bfbits(float f) {
  bf16 h = __float2bfloat16(f);
  return *reinterpret_cast<short*>(&h);
}

// ---------------- fused fp32 -> bf16 conversion (all 4 tensors) ----------------
#define CVTN0 ((size_t)NROWS * DIMM)
#define CVTN1 ((size_t)DIMM * DIMM)
#define CVTN2 ((size_t)2 * NKV * HD * DIMM)
#define CVTN3 ((size_t)DIMM * DIMM)
__global__ void cvt_all(const float* __restrict__ x, const float* __restrict__ wq,
                        const float* __restrict__ wkv, const float* __restrict__ wo,
                        bf16* __restrict__ xb, bf16* __restrict__ wqb,
                        bf16* __restrict__ wkvb, bf16* __restrict__ wob) {
  const size_t total = CVTN0 + CVTN1 + CVTN2 + CVTN3;
  for (size_t i = ((size_t)blockIdx.x * blockDim.x + threadIdx.x) * 4; i < total;
       i += (size_t)gridDim.x * blockDim.x * 4) {
    const float* s;
    bf16* d;
    size_t off;
    if (i < CVTN0) { s = x; d = xb; off = i; }
    else if (i < CVTN0 + CVTN1) { s = wq; d = wqb; off = i - CVTN0; }
    else if (i < CVTN0 + CVTN1 + CVTN2) { s = wkv; d = wkvb; off = i - CVTN0 - CVTN1; }
    else { s = wo; d = wob; off = i - CVTN0 - CVTN1 - CVTN2; }
    const float4 v = *reinterpret_cast<const float4*>(s + off);
    alignas(8) bf16 t[4] = {__float2bfloat16(v.x), __float2bfloat16(v.y),
                            __float2bfloat16(v.z), __float2bfloat16(v.w)};
    *reinterpret_cast<uint2*>(d + off) = *reinterpret_cast<const uint2*>(t);
  }
}

__device__ inline void store_c(float* p, float v) { *p = v; }
__device__ inline void store_c(bf16* p, float v) { *p = __float2bfloat16(v); }

// ---------------- GEMM 256x256 tile, BK=64, 8 waves (R8-exact, proven 118us) ----
// 4 LDS planes (2buf x 2kh), stage plane g+3 during phase g, vmcnt(8) steady.
// One barrier per kh phase, 32 MFMA under setprio. st_16x32 swizzle both sides
// (zero bank conflicts, verified R7).
template <typename OutT>
__global__ __launch_bounds__(512, 2) void gemm256(
    const bf16* __restrict__ A, const bf16* __restrict__ B0,
    const bf16* __restrict__ B1, OutT* __restrict__ C,
    int N, int K, int Nsplit, int MI8) {
  __shared__ __align__(16) short As[2][2][256 * 32];
  __shared__ __align__(16) short Bs[2][2][256 * 32];
  const int tid = threadIdx.x;
  const int w = tid >> 6, l = tid & 63;
  const int bid = blockIdx.x;
  const int xcd = bid & 7, q = bid >> 3;
  const int mi = q % MI8, j = q / MI8;
  const int m0 = (xcd * MI8 + mi) * 256, n0 = j * 256;
  const bf16* Ap = A + (size_t)m0 * K;
  const bf16* Bp = (n0 < Nsplit) ? (B0 + (size_t)n0 * K)
                                 : (B1 + (size_t)(n0 - Nsplit) * K);
  const int wr = w >> 2, wc = w & 3;  // wave grid 2(M) x 4(N)
  const int lr = l & 15, lc = l >> 4;
  const int swz = lc ^ (((lr >> 3) & 1) << 1);  // st_16x32 read swizzle

  f32x4 acc[8][4] = {};
  const int KT = K >> 6;

  auto stage = [&](int kt, int kh, int buf) {
#pragma unroll
    for (int jj = 0; jj < 2; ++jj) {
      const int cbase = jj * 512 + w * 64;  // wave-uniform chunk base
      const int ch = cbase + l;
      const int row = ch >> 2, c = ch & 3;
      const int sc = c ^ (((row >> 3) & 1) << 1);  // source pre-swizzle
      const int gcol = kt * 64 + kh * 32 + sc * 8;
      gload_lds16(Ap + (size_t)row * K + gcol, (bf16*)&As[buf][kh][cbase * 8]);
      gload_lds16(Bp + (size_t)row * K + gcol, (bf16*)&Bs[buf][kh][cbase * 8]);
    }
  };

  stage(0, 0, 0);
  stage(0, 1, 0);
  stage(1, 0, 1);

  for (int kt = 0; kt < KT; ++kt) {
    const int cur = kt & 1;
#pragma unroll
    for (int kh = 0; kh < 2; ++kh) {
      if (kt < KT - 1) {
        asm volatile("s_waitcnt vmcnt(8)" ::: "memory");
      } else if (kh == 0) {
        asm volatile("s_waitcnt vmcnt(4)" ::: "memory");
      } else {
        asm volatile("s_waitcnt vmcnt(0)" ::: "memory");
      }
      __builtin_amdgcn_s_barrier();
      __builtin_amdgcn_sched_barrier(0);

      short8 a[8], b[4];
      const short* Ab = &As[cur][kh][0];
      const short* Bb = &Bs[cur][kh][0];
#pragma unroll
      for (int mr = 0; mr < 8; ++mr)
        a[mr] = *(const short8*)&Ab[(wr * 128 + mr * 16 + lr) * 32 + swz * 8];
#pragma unroll
      for (int nr = 0; nr < 4; ++nr)
        b[nr] = *(const short8*)&Bb[(wc * 64 + nr * 16 + lr) * 32 + swz * 8];

      {
        const int g = 2 * kt + kh + 3;
        const int st = g >> 1;
        if (st < KT) stage(st, g & 1, st & 1);
      }

      __builtin_amdgcn_s_setprio(1);
#pragma unroll
      for (int mr = 0; mr < 8; ++mr)
#pragma unroll
        for (int nr = 0; nr < 4; ++nr)
          acc[mr][nr] = __builtin_amdgcn_mfma_f32_16x16x32_bf16(
              a[mr], b[nr], acc[mr][nr], 0, 0, 0);
      __builtin_amdgcn_s_setprio(0);
    }
  }

  const int cr4 = (l >> 4) * 4;
#pragma unroll
  for (int mr = 0; mr < 8; ++mr)
#pragma unroll
    for (int nr = 0; nr < 4; ++nr)
#pragma unroll
      for (int r = 0; r < 4; ++r) {
        const int row = m0 + wr * 128 + mr * 16 + cr4 + r;
        const int col = n0 + wc * 64 + nr * 16 + lr;
        store_c(&C[(size_t)row * N + col], acc[mr][nr][r]);
      }
}

// ---------------- fused RoPE (k heads ONLY; q-rope moved into attn) + V transpose
#define NVT ((SEQ / 64) * 2 * 16)            // 1024 vtrans blocks
#define NRP ((NROWS * 4 * 8) / 256)          // 1024 k-rope blocks
__global__ __launch_bounds__(256) void prep_kernel(bf16* __restrict__ qkv,
                                                   bf16* __restrict__ vtg) {
  if ((int)blockIdx.x < NVT) {
    __shared__ short T[64 * 72];
    const int bz = blockIdx.x >> 6;
    const int rem = blockIdx.x & 63;
    const int si = (rem >> 1) * 64;
    const int di = (rem & 1) * 64;
    const int b = bz >> 2, kvh = bz & 3;
    const int t = threadIdx.x;
    const int r = t >> 2, c2 = (t & 3) * 2;
    const bf16* src =
        qkv + (size_t)(b * SEQ + si + r) * QKVN + DIMM + NKV * HD + kvh * 128 + di;
#pragma unroll
    for (int i = 0; i < 2; ++i)
      *(short8*)&T[r * 72 + (c2 + i) * 8] = *(const short8*)(src + (c2 + i) * 8);
    __syncthreads();
#pragma unroll
    for (int i = 0; i < 2; ++i) {
      short8 v;
      const int s8 = (c2 + i) * 8;
#pragma unroll
      for (int j = 0; j < 8; ++j) v[j] = T[(s8 + j) * 72 + r];
      *(short8*)(vtg + (size_t)(kvh * 128 + di + r) * NROWS + b * SEQ + si + s8) = v;
    }
  } else {
    const int idx = ((int)blockIdx.x - NVT) * blockDim.x + threadIdx.x;
    const int dc = idx & 7;              // 8-pair chunk
    const int slot = (idx >> 3) & 3;     // 4 k heads
    const int row = idx >> 5;
    const size_t base = (size_t)row * QKVN + DIMM + slot * 128;
    const int pos = row & (SEQ - 1);
    short8 lo = *(const short8*)(qkv + base + dc * 8);
    short8 hi = *(const short8*)(qkv + base + 64 + dc * 8);
    short8 olo, ohi;
#pragma unroll
    for (int j = 0; j < 8; ++j) {
      const int d = dc * 8 + j;
      const float inv = exp2f((float)d * -0.2076205059304703f);  // log2(1e4)/64
      float sn, cs;
      __sincosf((float)pos * inv, &sn, &cs);
      const float flo = bf2f(lo[j]), fhi = bf2f(hi[j]);
      olo[j] = f2bfbits(flo * cs - fhi * sn);
      ohi[j] = f2bfbits(fhi * cs + flo * sn);
    }
    *(short8*)(qkv + base + dc * 8) = olo;
    *(short8*)(qkv + base + 64 + dc * 8) = ohi;
  }
}

// ---------------- Flash attention: 8 waves x 32 q-rows, KVBLK=64, swapped QK^T ----
// Q-RoPE + prescale applied IN-REGISTER at Q load (partner of frag s is frag s^4).
__global__ __launch_bounds__(512, 2) void attn_kernel(
    const bf16* __restrict__ qkv, const bf16* __restrict__ vtg,
    bf16* __restrict__ aout) {
  __shared__ __align__(16) short KsL[2][64 * 128];
  __shared__ __align__(16) short VtL[2][128 * 64];
  const int tid = threadIdx.x, w = tid >> 6, l = tid & 63;
  const int lq = l & 31, hi = l >> 5;
  const int id = blockIdx.x;
  const int half = id >> 8, rr = id & 255;
  const int bh = (rr >> 3) + half * 32;
  const int j = rr & 7;
  const int qb = half ? j : 7 - j;
  const int b = bh >> 4, h = bh & 15, kvh = h >> 2;
  const int qw0 = qb * 256 + w * 32;
  const int qg = qw0 + lq;

  // ---- load raw Q, apply RoPE + scale*log2e in-register ----
  short8 qf[8];
  {
    const bf16* qptr = qkv + (size_t)(b * SEQ + qg) * QKVN + h * 128 + hi * 8;
    short8 qraw[8];
#pragma unroll
    for (int s = 0; s < 8; ++s) qraw[s] = *(const short8*)(qptr + s * 16);
    float cs4[4][8], sn4[4][8];
#pragma unroll
    for (int sq = 0; sq < 4; ++sq)
#pragma unroll
      for (int jj = 0; jj < 8; ++jj) {
        const int dd = sq * 16 + hi * 8 + jj;
        const float inv = exp2f((float)dd * -0.2076205059304703f);
        float sn, cs;
        __sincosf((float)qg * inv, &sn, &cs);
        cs4[sq][jj] = cs * 0.12751879895f;  // *= scale*log2e
        sn4[sq][jj] = sn * 0.12751879895f;
      }
#pragma unroll
    for (int s = 0; s < 8; ++s)
#pragma unroll
      for (int jj = 0; jj < 8; ++jj) {
        const float f = bf2f(qraw[s][jj]);
        const float g = bf2f(qraw[s ^ 4][jj]);
        const float v = (s < 4) ? f * cs4[s][jj] - g * sn4[s][jj]
                                : f * cs4[s & 3][jj] + g * sn4[s & 3][jj];
        qf[s][jj] = f2bfbits(v);
      }
  }

  f32x16 o[4] = {};
  float m = -1e30f, lsum = 0.f;
  const int ntiles = qb * 4 + 4;

  const bf16* Kgb = qkv + (size_t)(b * SEQ) * QKVN + DIMM + kvh * 128;
  const bf16* Vgb = vtg + (size_t)kvh * 128 * NROWS + b * SEQ;

  auto stage = [&](int kt, int buf) {
#pragma unroll
    for (int rd = 0; rd < 2; ++rd) {
      const int cb = (w * 2 + rd) * 64;
      {
        const int lc = cb + l, k = lc >> 4, c = lc & 15;
        gload_lds16(Kgb + (size_t)(kt * 64 + k) * QKVN + ((c ^ (k & 7)) * 8),
                    (bf16*)&KsL[buf][cb * 8]);
      }
      {
        const int lc = cb + l, d = lc >> 3, c = lc & 7;
        gload_lds16(Vgb + (size_t)d * NROWS + kt * 64 + ((c ^ (d & 7)) * 8),
                    (bf16*)&VtL[buf][cb * 8]);
      }
    }
  };

  stage(0, 0);
  asm volatile("s_waitcnt vmcnt(0)" ::: "memory");
  __builtin_amdgcn_s_barrier();
  __builtin_amdgcn_sched_barrier(0);

  for (int kt = 0; kt < ntiles; ++kt) {
    const int cur = kt & 1;
    if (kt + 1 < ntiles) stage(kt + 1, cur ^ 1);

    if (kt * 64 <= qw0 + 31) {
      f32x16 st[2];
#pragma unroll
      for (int ks = 0; ks < 2; ++ks) {
        const short* kb = &KsL[cur][(ks * 32 + lq) * 128];
        const int r7 = lq & 7;
        f32x16 acc = {};
        __builtin_amdgcn_s_setprio(1);
#pragma unroll
        for (int s = 0; s < 8; ++s) {
          const short8 kf = *(const short8*)&kb[((2 * s + hi) ^ r7) * 8];
          acc = __builtin_amdgcn_mfma_f32_32x32x16_bf16(kf, qf[s], acc, 0, 0, 0);
        }
        __builtin_amdgcn_s_setprio(0);
        st[ks] = acc;
      }
      if (kt * 64 + 63 > qw0) {
#pragma unroll
        for (int ks = 0; ks < 2; ++ks)
#pragma unroll
          for (int r = 0; r < 16; ++r) {
            const int kg = kt * 64 + ks * 32 + (r & 3) + 8 * (r >> 2) + 4 * hi;
            if (kg > qg) st[ks][r] = -1e30f;
          }
      }
      float t[16];
#pragma unroll
      for (int r = 0; r < 16; ++r) t[r] = fmaxf(st[0][r], st[1][r]);
#pragma unroll
      for (int d2 = 8; d2 > 0; d2 >>= 1)
#pragma unroll
        for (int r = 0; r < 8; ++r)
          if (r < d2) t[r] = fmaxf(t[r], t[r + d2]);
      float pm = fmaxf(t[0], __shfl_xor(t[0], 32));
      if (!__all(pm <= m + 11.0f)) {
        const float mnew = fmaxf(m, pm);
        const float fsc = __builtin_amdgcn_exp2f(m - mnew);
        m = mnew;
        lsum *= fsc;
#pragma unroll
        for (int r = 0; r < 16; ++r) {
          const float fq = __shfl(fsc, (r & 3) + 8 * (r >> 2) + 4 * hi);
#pragma unroll
          for (int db = 0; db < 4; ++db) o[db][r] *= fq;
        }
      }
      short8 pa[4];
#pragma unroll
      for (int ks = 0; ks < 2; ++ks) {
        float p[16];
        float s0 = 0.f, s1 = 0.f, s2 = 0.f, s3 = 0.f;
#pragma unroll
        for (int r = 0; r < 16; r += 4) {
          p[r] = __builtin_amdgcn_exp2f(st[ks][r] - m);         s0 += p[r];
          p[r + 1] = __builtin_amdgcn_exp2f(st[ks][r + 1] - m); s1 += p[r + 1];
          p[r + 2] = __builtin_amdgcn_exp2f(st[ks][r + 2] - m); s2 += p[r + 2];
          p[r + 3] = __builtin_amdgcn_exp2f(st[ks][r + 3] - m); s3 += p[r + 3];
        }
        lsum += (s0 + s1) + (s2 + s3);
#pragma unroll
        for (int hf = 0; hf < 2; ++hf) {
          unsigned x0 = cvtpk(p[hf * 8 + 0], p[hf * 8 + 1]);
          unsigned y0 = cvtpk(p[hf * 8 + 4], p[hf * 8 + 5]);
          unsigned x1 = cvtpk(p[hf * 8 + 2], p[hf * 8 + 3]);
          unsigned y1 = cvtpk(p[hf * 8 + 6], p[hf * 8 + 7]);
          pswap(x0, y0);
          pswap(x1, y1);
          union { u32x4 u; short8 s; } pk;
          pk.u = u32x4{x0, x1, y0, y1};
          pa[ks * 2 + hf] = pk.s;
        }
      }
      __builtin_amdgcn_s_setprio(1);
#pragma unroll
      for (int s = 0; s < 4; ++s) {
        const int cc = ((2 * s + hi) ^ (lq & 7)) * 8;
#pragma unroll
        for (int db = 0; db < 4; ++db) {
          const short8 vb = *(const short8*)&VtL[cur][(db * 32 + lq) * 64 + cc];
          o[db] = __builtin_amdgcn_mfma_f32_32x32x16_bf16(pa[s], vb, o[db], 0, 0, 0);
        }
      }
      __builtin_amdgcn_s_setprio(0);
    }

    asm volatile("s_waitcnt vmcnt(0)" ::: "memory");
    __builtin_amdgcn_s_barrier();
    __builtin_amdgcn_sched_barrier(0);
  }

  const float lf = lsum + __shfl_xor(lsum, 32);
#pragma unroll
  for (int r = 0; r < 16; ++r) {
    const int qr = (r & 3) + 8 * (r >> 2) + 4 * hi;
    const float linv = 1.0f / __shfl(lf, qr);
    bf16* op = aout + (size_t)(b * SEQ + qw0 + qr) * DIMM + h * 128 + lq;
#pragma unroll
    for (int db = 0; db < 4; ++db)
      op[db * 32] = __float2bfloat16(o[db][r] * linv);
  }
}

// ---------------- launcher ----------------
extern "C" void kernel_launch(void* const* d_in, const int* in_sizes, int n_in,
                              void* d_out, int out_size, void* d_ws, size_t ws_size,
                              hipStream_t stream) {
  const float* x = (const float*)d_in[0];
  const float* Wq = (const float*)d_in[1];
  const float* Wkv = (const float*)d_in[2];
  const float* Wo = (const float*)d_in[3];
  float* out = (float*)d_out;

  bf16* xb = (bf16*)d_ws;                          // 8192*2048
  bf16* Wqb = xb + (size_t)NROWS * DIMM;           // 2048*2048
  bf16* Wkvb = Wqb + (size_t)DIMM * DIMM;          // 1024*2048
  bf16* Wob = Wkvb + (size_t)2 * NKV * HD * DIMM;  // 2048*2048
  bf16* attn = Wob + (size_t)DIMM * DIMM;          // 8192*2048
  bf16* qkv = (bf16*)d_out;                        // 50.3MB scratch in d_out
  bf16* vtg = (bf16*)d_out + (size_t)NROWS * QKVN; // 8MB more, still in d_out

  cvt_all<<<2048, 256, 0, stream>>>(x, Wq, Wkv, Wo, xb, Wqb, Wkvb, Wob);

  gemm256<bf16><<<dim3((NROWS / 256) * (QKVN / 256)), 512, 0, stream>>>(
      xb, Wqb, Wkvb, qkv, QKVN, DIMM, DIMM, (NROWS / 256) / 8);

  prep_kernel<<<NVT + NRP, 256, 0, stream>>>(qkv, vtg);

  attn_kernel<<<dim3(512), 512, 0, stream>>>(qkv, vtg, attn);

  gemm256<float><<<dim3((NROWS / 256) * (DIMM / 256)), 512, 0, stream>>>(
      attn, Wob, Wob, out, DIMM, DIMM, DIMM, (NROWS / 256) / 8);
}